// Round 13
// baseline (139.894 us; speedup 1.0000x reference)
//
#include <hip/hip_runtime.h>
#include <hip/hip_bf16.h>
#include <math.h>

#define BB 4
#define LL 1024
#define DD 256
#define KK 64
#define NN (BB*LL)   // 4096 tokens

typedef __attribute__((ext_vector_type(8))) short short8;
typedef __attribute__((ext_vector_type(4))) float f32x4;

__device__ __forceinline__ short f2bs(float f){
    union { __hip_bfloat16 h; short s; } u;
    u.h = __float2bfloat16(f);
    return u.s;
}
__device__ __forceinline__ float bs2f(short s){
    union { unsigned int u; float f; } v;
    v.u = ((unsigned int)(unsigned short)s) << 16;
    return v.f;
}

// ---------------------------------------------------------------------------
// Kernel P: weight transpose + bf16 cast, x -> bf16. (No R zeroing needed:
// partial buffers are fully written by construction, r6-verified invariant.)
// ---------------------------------------------------------------------------
__global__ __launch_bounds__(256)
void prep_kernel(const float* __restrict__ x,
                 const float* __restrict__ W1, const float* __restrict__ Wv,
                 const float* __restrict__ Wo, const float* __restrict__ W2,
                 const float* __restrict__ Wa,
                 short* __restrict__ xb,
                 short* __restrict__ W1t, short* __restrict__ Wvt,
                 short* __restrict__ Wot, short* __restrict__ W2t,
                 short* __restrict__ Wat)
{
    int o = blockIdx.x * 256 + threadIdx.x;
    if (o < NN*DD){ xb[o] = f2bs(x[o]); return; }
    o -= NN*DD;
    if (o < 3*DD*DD){                     // 256x256 transposes
        int m = o / (DD*DD);
        int e = o - m*DD*DD;
        int n = e >> 8, k = e & 255;
        const float* src = (m==0) ? W1 : (m==1) ? Wv : Wo;
        short* dst = (m==0) ? W1t : (m==1) ? Wvt : Wot;
        dst[n*DD + k] = f2bs(src[k*DD + n]);
        return;
    }
    o -= 3*DD*DD;
    if (o < 2*KK*DD){                     // 64x256 transposes
        int m = o >> 14;
        int e = o & 16383;
        int n = e >> 8, k = e & 255;
        const float* src = (m==0) ? W2 : Wa;
        short* dst = (m==0) ? W2t : Wat;
        dst[n*DD + k] = f2bs(src[k*KK + n]);
    }
}

// ---------------------------------------------------------------------------
// Kernel A: encoder via MFMA + fused V-transpose. (r12/best, unchanged.)
// MFMA layouts (verified): A[m=lane&15][k=quad*8+j]; B[n=lane&15][k=quad*8+j];
// C/D: col=lane&15, row=quad*4+reg.
// ---------------------------------------------------------------------------
__global__ __launch_bounds__(256)
void encode_kernel(const short* __restrict__ xb, const float* __restrict__ pos,
                   const short* __restrict__ W1t, const short* __restrict__ Wvt,
                   const short* __restrict__ W2t, const short* __restrict__ Wat,
                   const float* __restrict__ b1, const float* __restrict__ bv,
                   const float* __restrict__ b2, const float* __restrict__ ba,
                   short* __restrict__ Pb, short* __restrict__ Vt)
{
    const int t = threadIdx.x;
    const int w = t >> 6, lane = t & 63;
    const int m16 = lane & 15, quad = lane >> 4;
    const int tok0 = blockIdx.x * 16;
    const int bsel = tok0 >> 10;
    const int l0   = tok0 & 1023;

    __shared__ __align__(16) short hsb[16][264];
    __shared__ __align__(16) short vsb[16][264];

    short8 aX[8];
    {
        const short* xr = xb + (size_t)(tok0 + m16)*DD + quad*8;
        #pragma unroll
        for (int kk = 0; kk < 8; kk++) aX[kk] = *(const short8*)(xr + kk*32);
    }

    f32x4 accH[4], accV[4];
    #pragma unroll
    for (int i = 0; i < 4; i++){ accH[i] = (f32x4){0,0,0,0}; accV[i] = (f32x4){0,0,0,0}; }
    #pragma unroll
    for (int kk = 0; kk < 8; kk++){
        const short* p1 = W1t + (size_t)(w*64 + m16)*DD + kk*32 + quad*8;
        const short* pv = Wvt + (size_t)(w*64 + m16)*DD + kk*32 + quad*8;
        #pragma unroll
        for (int ns = 0; ns < 4; ns++){
            accH[ns] = __builtin_amdgcn_mfma_f32_16x16x32_bf16(
                           aX[kk], *(const short8*)(p1 + ns*16*DD), accH[ns], 0,0,0);
            accV[ns] = __builtin_amdgcn_mfma_f32_16x16x32_bf16(
                           aX[kk], *(const short8*)(pv + ns*16*DD), accV[ns], 0,0,0);
        }
    }
    #pragma unroll
    for (int ns = 0; ns < 4; ns++){
        int col = w*64 + ns*16 + m16;
        float bb1 = b1[col], bbv = bv[col];
        #pragma unroll
        for (int r2 = 0; r2 < 4; r2++){
            int row = quad*4 + r2;
            float hx = accH[ns][r2] + bb1;
            hsb[row][col] = f2bs(0.5f*hx*(1.0f + erff(hx*0.70710678118f)));
            vsb[row][col] = f2bs(accV[ns][r2] + bbv);
        }
    }
    __syncthreads();

    {   // fused V transpose: thread t owns d=t
        short8 v0, v1;
        #pragma unroll
        for (int r = 0; r < 8; r++) v0[r] = vsb[r][t];
        #pragma unroll
        for (int r = 0; r < 8; r++) v1[r] = vsb[8+r][t];
        short* dst = Vt + (((size_t)bsel*256 + t) << 10) + l0;
        *(short8*)dst = v0;
        *(short8*)(dst + 8) = v1;
    }

    f32x4 accT = (f32x4){0,0,0,0}, accA = (f32x4){0,0,0,0};
    {
        const short* p2 = W2t + (size_t)(w*16 + m16)*DD + quad*8;
        const short* pa = Wat + (size_t)(w*16 + m16)*DD + quad*8;
        #pragma unroll
        for (int kk = 0; kk < 8; kk++){
            short8 aH = *(const short8*)&hsb[m16][kk*32 + quad*8];
            accT = __builtin_amdgcn_mfma_f32_16x16x32_bf16(
                       aH, *(const short8*)(p2 + kk*32), accT, 0,0,0);
            accA = __builtin_amdgcn_mfma_f32_16x16x32_bf16(
                       aX[kk], *(const short8*)(pa + kk*32), accA, 0,0,0);
        }
    }
    const int k = w*16 + m16;
    float bb2 = b2[k], bba = ba[k];
    const float PI_ = 3.14159265358979323846f;
    #pragma unroll
    for (int r2 = 0; r2 < 4; r2++){
        int tok = tok0 + quad*4 + r2;
        float cp = tanhf(accT[r2] + bb2) * PI_;
        float ph = cp + pos[(tok & (LL-1))*KK + k];
        float za = accA[r2] + bba;
        float amp = ((za > 20.f) ? za : log1pf(expf(za))) + 0.1f;
        float sn, cs;
        sincosf(ph, &sn, &cs);
        Pb[(size_t)tok*128 + k]      = f2bs(amp*cs);
        Pb[(size_t)tok*128 + 64 + k] = f2bs(amp*sn);
    }
}

// ---------------------------------------------------------------------------
// Kernel B: causal phasor mixing via MFMA with LDS-staged tiles (r9/r12) —
// ATOMIC-FREE: block (b,T,y) writes its partial O (64x256) as bf16 with
// coalesced stores (via LDS repack) into partial buffer y. Invariant:
// partial y is written for row-tile T iff y <= T/4, i.e. for row l iff
// y <= floor(l/256) — out sums exactly those, no zero-init needed.
// ---------------------------------------------------------------------------
__global__ __launch_bounds__(256)
void mix_kernel(const short* __restrict__ Pb, const short* __restrict__ Vt,
                short* __restrict__ Rp)
{
    const int t    = threadIdx.x;
    const int bb   = blockIdx.x >> 4;
    const int T    = blockIdx.x & 15;
    const int cs   = blockIdx.y * 256;
    if (cs > T*64) return;                 // block-uniform early exit

    const int w    = t >> 6;
    const int lane = t & 63;
    const int m16  = lane & 15;
    const int quad = lane >> 4;
    const int mrow0 = T*64 + w*16;

    // arena: mix staging (sP 17408 + sV 36864 + sS 9216 = 63488) aliased
    // with the post-loop repack buffer sO (4 waves x 16 x 264 = 33792 B).
    __shared__ __align__(16) char smem[63488];
    short (*sP)[136]    = (short(*)[136])smem;
    short (*sV)[72]     = (short(*)[72])(smem + 17408);
    short (*sS)[16][72] = (short(*)[16][72])(smem + 54272);
    short (*sO)[264]    = (short(*)[264])smem;     // aliases sP/sV after loop

    f32x4 accO[16];
    #pragma unroll
    for (int i = 0; i < 16; i++) accO[i] = (f32x4){0.f,0.f,0.f,0.f};

    const short* PbB = Pb + (size_t)bb * 1024 * 128;
    const short* VtB = Vt + (size_t)bb * 256 * 1024;

    short8 aP[4];
    {
        const short* ar = PbB + (size_t)(mrow0 + m16) * 128 + quad*8;
        #pragma unroll
        for (int kk = 0; kk < 4; kk++) aP[kk] = *(const short8*)(ar + kk*32);
    }

    const int cend = min(cs + 192, T*64);
    for (int c0 = cs; c0 <= cend; c0 += 64){
        __syncthreads();   // protect previous iter's LDS reads
        {
            int j = t >> 2, seg = t & 3;
            const short* src = PbB + (size_t)(c0 + j)*128 + seg*32;
            #pragma unroll
            for (int q = 0; q < 4; q++)
                *(short8*)&sP[j][seg*32 + q*8] = *(const short8*)(src + q*8);
        }
        {
            int seg = t & 7;
            #pragma unroll
            for (int pass = 0; pass < 8; pass++){
                int d = pass*32 + (t >> 3);
                *(short8*)&sV[d][seg*8] =
                    *(const short8*)(VtB + (size_t)d*1024 + c0 + seg*8);
            }
        }
        __syncthreads();

        f32x4 accS[4];
        #pragma unroll
        for (int n = 0; n < 4; n++) accS[n] = (f32x4){0.f,0.f,0.f,0.f};
        #pragma unroll
        for (int ns = 0; ns < 4; ns++){
            #pragma unroll
            for (int kk = 0; kk < 4; kk++){
                short8 bP = *(const short8*)&sP[ns*16 + m16][kk*32 + quad*8];
                accS[ns] = __builtin_amdgcn_mfma_f32_16x16x32_bf16(
                               aP[kk], bP, accS[ns], 0, 0, 0);
            }
        }
        if (c0 == T*64){
            #pragma unroll
            for (int ns = 0; ns < 4; ns++){
                int ccol = c0 + ns*16 + m16;
                #pragma unroll
                for (int r2 = 0; r2 < 4; r2++){
                    int rrow = mrow0 + quad*4 + r2;
                    float v = (ccol <= rrow) ? accS[ns][r2] : 0.f;
                    sS[w][quad*4 + r2][ns*16 + m16] = f2bs(v);
                }
            }
        } else {
            #pragma unroll
            for (int ns = 0; ns < 4; ns++)
                #pragma unroll
                for (int r2 = 0; r2 < 4; r2++)
                    sS[w][quad*4 + r2][ns*16 + m16] = f2bs(accS[ns][r2]);
        }
        short8 aS0 = *(const short8*)&sS[w][m16][quad*8];
        short8 aS1 = *(const short8*)&sS[w][m16][32 + quad*8];
        #pragma unroll
        for (int ns = 0; ns < 16; ns++){
            short8 b0  = *(const short8*)&sV[ns*16 + m16][quad*8];
            short8 b1v = *(const short8*)&sV[ns*16 + m16][32 + quad*8];
            accO[ns] = __builtin_amdgcn_mfma_f32_16x16x32_bf16(aS0, b0,  accO[ns], 0,0,0);
            accO[ns] = __builtin_amdgcn_mfma_f32_16x16x32_bf16(aS1, b1v, accO[ns], 0,0,0);
        }
    }

    // ---- repack accO (C-layout) -> bf16 row-major via LDS, store coalesced ----
    __syncthreads();                       // arena reuse boundary
    #pragma unroll
    for (int ns = 0; ns < 16; ns++)
        #pragma unroll
        for (int r2 = 0; r2 < 4; r2++)
            sO[w*16 + quad*4 + r2][ns*16 + m16] = f2bs(accO[ns][r2]);
    __syncthreads();

    short* dst = Rp + (size_t)blockIdx.y * NN * DD
                    + ((size_t)bb*1024 + T*64) * DD;
    {
        int row = t >> 2, seg = t & 3;     // 4 threads per 512-B row
        #pragma unroll
        for (int q = 0; q < 8; q++)
            *(short8*)(dst + (size_t)row*DD + seg*64 + q*8) =
                *(const short8*)&sO[row][seg*64 + q*8];
    }
}

// ---------------------------------------------------------------------------
// Kernel C: sum bf16 partials + /sqrt((l+1)K) + LayerNorm + Wo(MFMA) +
// residual. Valid partials for token tile at l0: p = 0..(l0>>8).
// ---------------------------------------------------------------------------
__global__ __launch_bounds__(256)
void out_kernel(const short* __restrict__ Rp, const float* __restrict__ x,
                const float* __restrict__ ln_g, const float* __restrict__ ln_b,
                const short* __restrict__ Wot, const float* __restrict__ bo,
                float* __restrict__ out)
{
    const int t = threadIdx.x;
    const int w = t >> 6, lane = t & 63;
    const int m16 = lane & 15, quad = lane >> 4;
    const int tok0 = blockIdx.x * 16;
    const int pmax = (tok0 & 1023) >> 8;   // valid partials: 0..pmax

    __shared__ float rs[16][DD];
    __shared__ __align__(16) short rnb[16][264];
    __shared__ float stats[16][2];

    for (int i = t; i < 16*DD; i += 256){
        int r = i >> 8;
        int l = (tok0 + r) & (LL-1);
        float s = 0.f;
        for (int p = 0; p <= pmax; p++)
            s += bs2f(Rp[(size_t)p*NN*DD + (size_t)tok0*DD + i]);
        rs[r][i&255] = s * rsqrtf((float)(l+1) * (float)KK);
    }
    __syncthreads();

    #pragma unroll
    for (int rr = 0; rr < 4; rr++){
        int r = w*4 + rr;
        float s = 0.f, ss = 0.f;
        #pragma unroll
        for (int q = 0; q < 4; q++){
            float v = rs[r][q*64 + lane];   // stride-64: 2-way alias, free
            s += v; ss += v*v;
        }
        for (int off = 32; off; off >>= 1){
            s  += __shfl_down(s, off);
            ss += __shfl_down(ss, off);
        }
        if (lane == 0){
            float mu = s * (1.0f/DD);
            float var = ss * (1.0f/DD) - mu*mu;
            stats[r][0] = mu;
            stats[r][1] = rsqrtf(var + 1e-5f);
        }
    }
    __syncthreads();

    for (int i = t; i < 16*DD; i += 256){
        int r = i >> 8, c = i & 255;
        rnb[r][c] = f2bs((rs[r][c] - stats[r][0]) * stats[r][1] * ln_g[c] + ln_b[c]);
    }
    __syncthreads();

    f32x4 acc[4];
    #pragma unroll
    for (int i = 0; i < 4; i++) acc[i] = (f32x4){0,0,0,0};
    #pragma unroll
    for (int kk = 0; kk < 8; kk++){
        short8 aR = *(const short8*)&rnb[m16][kk*32 + quad*8];
        const short* po = Wot + (size_t)(w*64 + m16)*DD + kk*32 + quad*8;
        #pragma unroll
        for (int ns = 0; ns < 4; ns++)
            acc[ns] = __builtin_amdgcn_mfma_f32_16x16x32_bf16(
                          aR, *(const short8*)(po + ns*16*DD), acc[ns], 0,0,0);
    }
    #pragma unroll
    for (int ns = 0; ns < 4; ns++){
        int col = w*64 + ns*16 + m16;
        float bbo = bo[col];
        #pragma unroll
        for (int r2 = 0; r2 < 4; r2++){
            size_t idx = (size_t)(tok0 + quad*4 + r2)*DD + col;
            out[idx] = x[idx] + acc[ns][r2] + bbo;
        }
    }
}

// ---------------------------------------------------------------------------
extern "C" void kernel_launch(void* const* d_in, const int* in_sizes, int n_in,
                              void* d_out, int out_size, void* d_ws, size_t ws_size,
                              hipStream_t stream) {
    const float* x    = (const float*)d_in[0];
    const float* pos  = (const float*)d_in[1];
    const float* W1   = (const float*)d_in[2];
    const float* b1   = (const float*)d_in[3];
    const float* W2   = (const float*)d_in[4];
    const float* b2_  = (const float*)d_in[5];
    const float* Wa   = (const float*)d_in[6];
    const float* ba   = (const float*)d_in[7];
    const float* Wv   = (const float*)d_in[8];
    const float* bv   = (const float*)d_in[9];
    const float* ln_g = (const float*)d_in[10];
    const float* ln_b = (const float*)d_in[11];
    const float* Wo   = (const float*)d_in[12];
    const float* bo   = (const float*)d_in[13];

    short* Rp  = (short*)d_ws;                      // 4 x NN*DD bf16 (8 MB)
    short* Pb  = Rp  + (size_t)4*NN*DD;             // NN*128 bf16 (1 MB)
    short* Vt  = Pb  + (size_t)NN*128;              // NN*256 bf16 (2 MB)
    short* xb  = Vt  + (size_t)NN*256;              // NN*256 bf16 (2 MB)
    short* W1t = xb  + (size_t)NN*256;
    short* Wvt = W1t + DD*DD;
    short* Wot = Wvt + DD*DD;
    short* W2t = Wot + DD*DD;
    short* Wat = W2t + KK*DD;

    const int prep_n = NN*DD + 3*DD*DD + 2*KK*DD;   // 1,277,952
    prep_kernel<<<(prep_n + 255)/256, 256, 0, stream>>>(
        x, W1, Wv, Wo, W2, Wa, xb, W1t, Wvt, Wot, W2t, Wat);

    encode_kernel<<<NN/16, 256, 0, stream>>>(xb, pos, W1t, Wvt, W2t, Wat,
                                             b1, bv, b2_, ba, Pb, Vt);

    dim3 mixgrid(BB*16, 4);
    mix_kernel<<<mixgrid, 256, 0, stream>>>(Pb, Vt, Rp);
    out_kernel<<<NN/16, 256, 0, stream>>>(Rp, x, ln_g, ln_b, Wot, bo,
                                          (float*)d_out);
}

// Round 14
// 129.148 us; speedup vs baseline: 1.0832x; 1.0832x over previous
//
#include <hip/hip_runtime.h>
#include <hip/hip_bf16.h>
#include <math.h>

#define BB 4
#define LL 1024
#define DD 256
#define KK 64
#define NN (BB*LL)   // 4096 tokens

typedef __attribute__((ext_vector_type(8))) short short8;
typedef __attribute__((ext_vector_type(4))) float f32x4;

__device__ __forceinline__ short f2bs(float f){
    union { __hip_bfloat16 h; short s; } u;
    u.h = __float2bfloat16(f);
    return u.s;
}

// ---------------------------------------------------------------------------
// Kernel P: weight transpose + bf16 cast, and zero R. (xb staging removed:
// encode casts x in-register — x elements are single-use in the A-frags.)
// ---------------------------------------------------------------------------
__global__ __launch_bounds__(256)
void prep_kernel(const float* __restrict__ W1, const float* __restrict__ Wv,
                 const float* __restrict__ Wo, const float* __restrict__ W2,
                 const float* __restrict__ Wa,
                 short* __restrict__ W1t, short* __restrict__ Wvt,
                 short* __restrict__ Wot, short* __restrict__ W2t,
                 short* __restrict__ Wat, float* __restrict__ R)
{
    int o = blockIdx.x * 256 + threadIdx.x;
    if (o < 3*DD*DD){                     // 256x256 transposes
        int m = o / (DD*DD);
        int e = o - m*DD*DD;
        int n = e >> 8, k = e & 255;
        const float* src = (m==0) ? W1 : (m==1) ? Wv : Wo;
        short* dst = (m==0) ? W1t : (m==1) ? Wvt : Wot;
        dst[n*DD + k] = f2bs(src[k*DD + n]);
        return;
    }
    o -= 3*DD*DD;
    if (o < 2*KK*DD){                     // 64x256 transposes
        int m = o >> 14;
        int e = o & 16383;
        int n = e >> 8, k = e & 255;
        const float* src = (m==0) ? W2 : Wa;
        short* dst = (m==0) ? W2t : Wat;
        dst[n*DD + k] = f2bs(src[k*KK + n]);
        return;
    }
    o -= 2*KK*DD;
    if (o < (NN*DD)/4)                    // zero R (float4 granules)
        *(f32x4*)(R + (size_t)o*4) = (f32x4){0.f,0.f,0.f,0.f};
}

// ---------------------------------------------------------------------------
// Kernel A: encoder via MFMA + fused V-transpose. (r12/best structure;
// A-frags now loaded from fp32 x and converted in-register.)
// MFMA layouts (verified): A[m=lane&15][k=quad*8+j]; B[n=lane&15][k=quad*8+j];
// C/D: col=lane&15, row=quad*4+reg.
// ---------------------------------------------------------------------------
__global__ __launch_bounds__(256)
void encode_kernel(const float* __restrict__ x, const float* __restrict__ pos,
                   const short* __restrict__ W1t, const short* __restrict__ Wvt,
                   const short* __restrict__ W2t, const short* __restrict__ Wat,
                   const float* __restrict__ b1, const float* __restrict__ bv,
                   const float* __restrict__ b2, const float* __restrict__ ba,
                   short* __restrict__ Pb, short* __restrict__ Vt)
{
    const int t = threadIdx.x;
    const int w = t >> 6, lane = t & 63;
    const int m16 = lane & 15, quad = lane >> 4;
    const int tok0 = blockIdx.x * 16;
    const int bsel = tok0 >> 10;
    const int l0   = tok0 & 1023;

    __shared__ __align__(16) short hsb[16][264];
    __shared__ __align__(16) short vsb[16][264];

    short8 aX[8];
    {
        const float* xr = x + (size_t)(tok0 + m16)*DD + quad*8;
        #pragma unroll
        for (int kk = 0; kk < 8; kk++){
            f32x4 xa = *(const f32x4*)(xr + kk*32);
            f32x4 xc = *(const f32x4*)(xr + kk*32 + 4);
            short8 fr;
            fr[0]=f2bs(xa[0]); fr[1]=f2bs(xa[1]); fr[2]=f2bs(xa[2]); fr[3]=f2bs(xa[3]);
            fr[4]=f2bs(xc[0]); fr[5]=f2bs(xc[1]); fr[6]=f2bs(xc[2]); fr[7]=f2bs(xc[3]);
            aX[kk] = fr;
        }
    }

    f32x4 accH[4], accV[4];
    #pragma unroll
    for (int i = 0; i < 4; i++){ accH[i] = (f32x4){0,0,0,0}; accV[i] = (f32x4){0,0,0,0}; }
    #pragma unroll
    for (int kk = 0; kk < 8; kk++){
        const short* p1 = W1t + (size_t)(w*64 + m16)*DD + kk*32 + quad*8;
        const short* pv = Wvt + (size_t)(w*64 + m16)*DD + kk*32 + quad*8;
        #pragma unroll
        for (int ns = 0; ns < 4; ns++){
            accH[ns] = __builtin_amdgcn_mfma_f32_16x16x32_bf16(
                           aX[kk], *(const short8*)(p1 + ns*16*DD), accH[ns], 0,0,0);
            accV[ns] = __builtin_amdgcn_mfma_f32_16x16x32_bf16(
                           aX[kk], *(const short8*)(pv + ns*16*DD), accV[ns], 0,0,0);
        }
    }
    #pragma unroll
    for (int ns = 0; ns < 4; ns++){
        int col = w*64 + ns*16 + m16;
        float bb1 = b1[col], bbv = bv[col];
        #pragma unroll
        for (int r2 = 0; r2 < 4; r2++){
            int row = quad*4 + r2;
            float hx = accH[ns][r2] + bb1;
            hsb[row][col] = f2bs(0.5f*hx*(1.0f + erff(hx*0.70710678118f)));
            vsb[row][col] = f2bs(accV[ns][r2] + bbv);
        }
    }
    __syncthreads();

    {   // fused V transpose: thread t owns d=t
        short8 v0, v1;
        #pragma unroll
        for (int r = 0; r < 8; r++) v0[r] = vsb[r][t];
        #pragma unroll
        for (int r = 0; r < 8; r++) v1[r] = vsb[8+r][t];
        short* dst = Vt + (((size_t)bsel*256 + t) << 10) + l0;
        *(short8*)dst = v0;
        *(short8*)(dst + 8) = v1;
    }

    f32x4 accT = (f32x4){0,0,0,0}, accA = (f32x4){0,0,0,0};
    {
        const short* p2 = W2t + (size_t)(w*16 + m16)*DD + quad*8;
        const short* pa = Wat + (size_t)(w*16 + m16)*DD + quad*8;
        #pragma unroll
        for (int kk = 0; kk < 8; kk++){
            short8 aH = *(const short8*)&hsb[m16][kk*32 + quad*8];
            accT = __builtin_amdgcn_mfma_f32_16x16x32_bf16(
                       aH, *(const short8*)(p2 + kk*32), accT, 0,0,0);
            accA = __builtin_amdgcn_mfma_f32_16x16x32_bf16(
                       aX[kk], *(const short8*)(pa + kk*32), accA, 0,0,0);
        }
    }
    const int k = w*16 + m16;
    float bb2 = b2[k], bba = ba[k];
    const float PI_ = 3.14159265358979323846f;
    #pragma unroll
    for (int r2 = 0; r2 < 4; r2++){
        int tok = tok0 + quad*4 + r2;
        float cp = tanhf(accT[r2] + bb2) * PI_;
        float ph = cp + pos[(tok & (LL-1))*KK + k];
        float za = accA[r2] + bba;
        float amp = ((za > 20.f) ? za : log1pf(expf(za))) + 0.1f;
        float sn, cs;
        sincosf(ph, &sn, &cs);
        Pb[(size_t)tok*128 + k]      = f2bs(amp*cs);
        Pb[(size_t)tok*128 + 64 + k] = f2bs(amp*sn);
    }
}

// ---------------------------------------------------------------------------
// Kernel B: causal phasor mixing via MFMA with LDS-staged tiles. (r12, best)
// ---------------------------------------------------------------------------
__global__ __launch_bounds__(256)
void mix_kernel(const short* __restrict__ Pb, const short* __restrict__ Vt,
                float* __restrict__ R)
{
    const int t    = threadIdx.x;
    const int bb   = blockIdx.x >> 4;
    const int T    = blockIdx.x & 15;
    const int cs   = blockIdx.y * 256;
    if (cs > T*64) return;                 // block-uniform early exit

    const int w    = t >> 6;
    const int lane = t & 63;
    const int m16  = lane & 15;
    const int quad = lane >> 4;
    const int mrow0 = T*64 + w*16;

    __shared__ __align__(16) short sP[64][136];    // P_C tile, +8 pad
    __shared__ __align__(16) short sV[256][72];    // Vt slice, +8 pad
    __shared__ __align__(16) short sS[4][16][72];  // per-wave repack

    f32x4 accO[16];
    #pragma unroll
    for (int i = 0; i < 16; i++) accO[i] = (f32x4){0.f,0.f,0.f,0.f};

    const short* PbB = Pb + (size_t)bb * 1024 * 128;
    const short* VtB = Vt + (size_t)bb * 256 * 1024;

    short8 aP[4];
    {
        const short* ar = PbB + (size_t)(mrow0 + m16) * 128 + quad*8;
        #pragma unroll
        for (int kk = 0; kk < 4; kk++) aP[kk] = *(const short8*)(ar + kk*32);
    }

    const int cend = min(cs + 192, T*64);
    for (int c0 = cs; c0 <= cend; c0 += 64){
        __syncthreads();   // protect previous iter's LDS reads
        {
            int j = t >> 2, seg = t & 3;
            const short* src = PbB + (size_t)(c0 + j)*128 + seg*32;
            #pragma unroll
            for (int q = 0; q < 4; q++)
                *(short8*)&sP[j][seg*32 + q*8] = *(const short8*)(src + q*8);
        }
        {
            int seg = t & 7;
            #pragma unroll
            for (int pass = 0; pass < 8; pass++){
                int d = pass*32 + (t >> 3);
                *(short8*)&sV[d][seg*8] =
                    *(const short8*)(VtB + (size_t)d*1024 + c0 + seg*8);
            }
        }
        __syncthreads();

        f32x4 accS[4];
        #pragma unroll
        for (int n = 0; n < 4; n++) accS[n] = (f32x4){0.f,0.f,0.f,0.f};
        #pragma unroll
        for (int ns = 0; ns < 4; ns++){
            #pragma unroll
            for (int kk = 0; kk < 4; kk++){
                short8 bP = *(const short8*)&sP[ns*16 + m16][kk*32 + quad*8];
                accS[ns] = __builtin_amdgcn_mfma_f32_16x16x32_bf16(
                               aP[kk], bP, accS[ns], 0, 0, 0);
            }
        }
        if (c0 == T*64){
            #pragma unroll
            for (int ns = 0; ns < 4; ns++){
                int ccol = c0 + ns*16 + m16;
                #pragma unroll
                for (int r2 = 0; r2 < 4; r2++){
                    int rrow = mrow0 + quad*4 + r2;
                    float v = (ccol <= rrow) ? accS[ns][r2] : 0.f;
                    sS[w][quad*4 + r2][ns*16 + m16] = f2bs(v);
                }
            }
        } else {
            #pragma unroll
            for (int ns = 0; ns < 4; ns++)
                #pragma unroll
                for (int r2 = 0; r2 < 4; r2++)
                    sS[w][quad*4 + r2][ns*16 + m16] = f2bs(accS[ns][r2]);
        }
        short8 aS0 = *(const short8*)&sS[w][m16][quad*8];
        short8 aS1 = *(const short8*)&sS[w][m16][32 + quad*8];
        #pragma unroll
        for (int ns = 0; ns < 16; ns++){
            short8 b0  = *(const short8*)&sV[ns*16 + m16][quad*8];
            short8 b1v = *(const short8*)&sV[ns*16 + m16][32 + quad*8];
            accO[ns] = __builtin_amdgcn_mfma_f32_16x16x32_bf16(aS0, b0,  accO[ns], 0,0,0);
            accO[ns] = __builtin_amdgcn_mfma_f32_16x16x32_bf16(aS1, b1v, accO[ns], 0,0,0);
        }
    }

    float* Rb = R + (size_t)bb * 1024 * 256;
    #pragma unroll
    for (int ns = 0; ns < 16; ns++){
        #pragma unroll
        for (int r2 = 0; r2 < 4; r2++){
            int rrow = mrow0 + quad*4 + r2;
            atomicAdd(&Rb[(size_t)rrow*256 + ns*16 + m16], accO[ns][r2]);
        }
    }
}

// ---------------------------------------------------------------------------
// Kernel C: /sqrt((l+1)K) + LayerNorm + Wo(MFMA) + residual. (r12, best)
// ---------------------------------------------------------------------------
__global__ __launch_bounds__(256)
void out_kernel(const float* __restrict__ R, const float* __restrict__ x,
                const float* __restrict__ ln_g, const float* __restrict__ ln_b,
                const short* __restrict__ Wot, const float* __restrict__ bo,
                float* __restrict__ out)
{
    const int t = threadIdx.x;
    const int w = t >> 6, lane = t & 63;
    const int m16 = lane & 15, quad = lane >> 4;
    const int tok0 = blockIdx.x * 16;

    __shared__ float rs[16][DD];
    __shared__ __align__(16) short rnb[16][264];
    __shared__ float stats[16][2];

    for (int i = t; i < 16*DD; i += 256){
        int r = i >> 8;
        int l = (tok0 + r) & (LL-1);
        rs[r][i&255] = R[(size_t)tok0*DD + i] * rsqrtf((float)(l+1) * (float)KK);
    }
    __syncthreads();

    #pragma unroll
    for (int rr = 0; rr < 4; rr++){
        int r = w*4 + rr;
        float s = 0.f, ss = 0.f;
        #pragma unroll
        for (int q = 0; q < 4; q++){
            float v = rs[r][q*64 + lane];   // stride-64: 2-way alias, free
            s += v; ss += v*v;
        }
        for (int off = 32; off; off >>= 1){
            s  += __shfl_down(s, off);
            ss += __shfl_down(ss, off);
        }
        if (lane == 0){
            float mu = s * (1.0f/DD);
            float var = ss * (1.0f/DD) - mu*mu;
            stats[r][0] = mu;
            stats[r][1] = rsqrtf(var + 1e-5f);
        }
    }
    __syncthreads();

    for (int i = t; i < 16*DD; i += 256){
        int r = i >> 8, c = i & 255;
        rnb[r][c] = f2bs((rs[r][c] - stats[r][0]) * stats[r][1] * ln_g[c] + ln_b[c]);
    }
    __syncthreads();

    f32x4 acc[4];
    #pragma unroll
    for (int i = 0; i < 4; i++) acc[i] = (f32x4){0,0,0,0};
    #pragma unroll
    for (int kk = 0; kk < 8; kk++){
        short8 aR = *(const short8*)&rnb[m16][kk*32 + quad*8];
        const short* po = Wot + (size_t)(w*64 + m16)*DD + kk*32 + quad*8;
        #pragma unroll
        for (int ns = 0; ns < 4; ns++)
            acc[ns] = __builtin_amdgcn_mfma_f32_16x16x32_bf16(
                          aR, *(const short8*)(po + ns*16*DD), acc[ns], 0,0,0);
    }
    #pragma unroll
    for (int ns = 0; ns < 4; ns++){
        int col = w*64 + ns*16 + m16;
        float bbo = bo[col];
        #pragma unroll
        for (int r2 = 0; r2 < 4; r2++){
            size_t idx = (size_t)(tok0 + quad*4 + r2)*DD + col;
            out[idx] = x[idx] + acc[ns][r2] + bbo;
        }
    }
}

// ---------------------------------------------------------------------------
extern "C" void kernel_launch(void* const* d_in, const int* in_sizes, int n_in,
                              void* d_out, int out_size, void* d_ws, size_t ws_size,
                              hipStream_t stream) {
    const float* x    = (const float*)d_in[0];
    const float* pos  = (const float*)d_in[1];
    const float* W1   = (const float*)d_in[2];
    const float* b1   = (const float*)d_in[3];
    const float* W2   = (const float*)d_in[4];
    const float* b2_  = (const float*)d_in[5];
    const float* Wa   = (const float*)d_in[6];
    const float* ba   = (const float*)d_in[7];
    const float* Wv   = (const float*)d_in[8];
    const float* bv   = (const float*)d_in[9];
    const float* ln_g = (const float*)d_in[10];
    const float* ln_b = (const float*)d_in[11];
    const float* Wo   = (const float*)d_in[12];
    const float* bo   = (const float*)d_in[13];

    float* R   = (float*)d_ws;                      // NN*DD fp32 (4 MB)
    short* Pb  = (short*)(R + (size_t)NN*DD);       // NN*128 bf16 (1 MB)
    short* Vt  = Pb  + (size_t)NN*128;              // NN*256 bf16 (2 MB)
    short* W1t = Vt  + (size_t)NN*256;
    short* Wvt = W1t + DD*DD;
    short* Wot = Wvt + DD*DD;
    short* W2t = Wot + DD*DD;
    short* Wat = W2t + KK*DD;

    // prep: 5 weight transposes + zero R (xb staging removed)
    const int prep_n = 3*DD*DD + 2*KK*DD + (NN*DD)/4;  // 491,520
    prep_kernel<<<(prep_n + 255)/256, 256, 0, stream>>>(
        W1, Wv, Wo, W2, Wa, W1t, Wvt, Wot, W2t, Wat, R);

    encode_kernel<<<NN/16, 256, 0, stream>>>(x, pos, W1t, Wvt, W2t, Wat,
                                             b1, bv, b2_, ba, Pb, Vt);

    dim3 mixgrid(BB*16, 4);
    mix_kernel<<<mixgrid, 256, 0, stream>>>(Pb, Vt, R);
    out_kernel<<<NN/16, 256, 0, stream>>>(R, x, ln_g, ln_b, Wot, bo,
                                          (float*)d_out);
}